// Round 9
// baseline (104.931 us; speedup 1.0000x reference)
//
#include <hip/hip_runtime.h>

// TT Q-gather — pair-folded bf16 tables, 18 divergent loads per element.
//
//   v = V01[s0][s1][:]        (bf16 fold of G0*G1, 1MB)
//   v = v @ M23[s2][s3]       (bf16 fold of G2*G3, 8MB, matrix-contiguous)
//   v = v @ M45[s4][s5]       (bf16 fold of G4*G5, 8MB)
//   q = v . U67[s6][a7][:]    (bf16 fold of G6*G7, 1MB)
//
// Model (fits R1/R7/R8): gather cost ~72 cy per divergent wave-instr x
// 16 waves/CU + ~10us fixed (launches+build). R8 = 34 instrs; this = 18,
// all independent with upfront addresses -> max MLP.
//
// ws layout (ushort units):
//   V01 @ 0        : [s0][s1][8]     (1 MB)
//   U67 @ 524288   : [s6][s7][8]     (1 MB)
//   M23 @ 1048576  : [s2][s3][8][8]  (8 MB)
//   M45 @ 5242880  : [s4][s5][8][8]  (8 MB)

#define NN 256
#define RR 8
#define NR 2048   // N * R
#define U67_OFF 524288
#define M23_OFF 1048576
#define M45_OFF 5242880

__device__ __forceinline__ unsigned short f2bf_rne(float f) {
    unsigned int u = __float_as_uint(f);
    u += 0x7FFFu + ((u >> 16) & 1u);
    return (unsigned short)(u >> 16);
}

__device__ __forceinline__ uint4 pack8bf(const float* a) {
    return make_uint4(
        f2bf_rne(a[0]) | ((unsigned int)f2bf_rne(a[1]) << 16),
        f2bf_rne(a[2]) | ((unsigned int)f2bf_rne(a[3]) << 16),
        f2bf_rne(a[4]) | ((unsigned int)f2bf_rne(a[5]) << 16),
        f2bf_rne(a[6]) | ((unsigned int)f2bf_rne(a[7]) << 16));
}

// grid 1024 x 256:
//   bid 0..255   -> V01 row
//   bid 256..511 -> U67 row
//   bid 512..767 -> M23 (s2 = bid-512, s3 = t)
//   bid 768..1023-> M45 (s4 = bid-768, s5 = t)
__global__ __launch_bounds__(256) void build_tables(
    const float* __restrict__ G0, const float* __restrict__ G1,
    const float* __restrict__ G2, const float* __restrict__ G3,
    const float* __restrict__ G4, const float* __restrict__ G5,
    const float* __restrict__ G6, const float* __restrict__ G7,
    unsigned short* __restrict__ wsb) {
    const int t = threadIdx.x;
    const int bid = blockIdx.x;

    if (bid < NN) {
        // V01[n0][n1][s] = sum_r G0[n0,r] * G1[r,n1,s]
        const int n0 = bid, n1 = t;
        float acc[RR] = {0.f,0.f,0.f,0.f,0.f,0.f,0.f,0.f};
#pragma unroll
        for (int r = 0; r < RR; ++r) {
            float ar = G0[n0 * RR + r];
            const float4* p = (const float4*)(G1 + r * NR + n1 * RR);
            float4 x = p[0], y = p[1];
            acc[0] += ar * x.x; acc[1] += ar * x.y;
            acc[2] += ar * x.z; acc[3] += ar * x.w;
            acc[4] += ar * y.x; acc[5] += ar * y.y;
            acc[6] += ar * y.z; acc[7] += ar * y.w;
        }
        *(uint4*)(wsb + n0 * 2048 + n1 * 8) = pack8bf(acc);
    } else if (bid < 2 * NN) {
        // U67[n6][n7][r] = sum_s G6[r,n6,s] * G7[s,n7]
        const int n6 = bid - NN, n7 = t;
        float g7v[RR];
#pragma unroll
        for (int s = 0; s < RR; ++s) g7v[s] = G7[s * NN + n7];
        float u[RR];
#pragma unroll
        for (int r = 0; r < RR; ++r) {
            float acc = 0.f;
#pragma unroll
            for (int s = 0; s < RR; ++s)
                acc += G6[r * NR + n6 * RR + s] * g7v[s];
            u[r] = acc;
        }
        *(uint4*)(wsb + U67_OFF + n6 * 2048 + n7 * 8) = pack8bf(u);
    } else {
        // pair fold: C[r][s] = sum_m A[r][sa][m] * B[m][sb][s]
        const bool is23 = (bid < 3 * NN);
        const int sa = bid - (is23 ? 2 * NN : 3 * NN);
        const int sb = t;
        const float* __restrict__ A = is23 ? G2 : G4;
        const float* __restrict__ Bc = is23 ? G3 : G5;
        const size_t base =
            (is23 ? M23_OFF : M45_OFF) + ((size_t)sa * NN + sb) * 64;

        // load B[:,sb,:] (per-thread, coalesced chunks)
        float bmat[RR][RR];
#pragma unroll
        for (int m = 0; m < RR; ++m) {
            const float4* p = (const float4*)(Bc + m * NR + sb * RR);
            float4 x = p[0], y = p[1];
            bmat[m][0] = x.x; bmat[m][1] = x.y;
            bmat[m][2] = x.z; bmat[m][3] = x.w;
            bmat[m][4] = y.x; bmat[m][5] = y.y;
            bmat[m][6] = y.z; bmat[m][7] = y.w;
        }
#pragma unroll
        for (int r = 0; r < RR; ++r) {
            float c[RR] = {0.f,0.f,0.f,0.f,0.f,0.f,0.f,0.f};
#pragma unroll
            for (int m = 0; m < RR; ++m) {
                float a = A[r * NR + sa * RR + m];   // wave-uniform -> scalar
#pragma unroll
                for (int s = 0; s < RR; ++s) c[s] += a * bmat[m][s];
            }
            *(uint4*)(wsb + base + r * 8) = pack8bf(c);
        }
    }
}

#define BF2F_LO(u) __uint_as_float((u) << 16)
#define BF2F_HI(u) __uint_as_float((u) & 0xFFFF0000u)

// v (fp32 x8) = v @ M where M = 8 preloaded uint4 rows m0..m7
#define MATVEC(m0,m1,m2,m3,m4,m5,m6,m7)                                     \
    do {                                                                    \
        float nv0 = 0.f, nv1 = 0.f, nv2 = 0.f, nv3 = 0.f;                   \
        float nv4 = 0.f, nv5 = 0.f, nv6 = 0.f, nv7 = 0.f;                   \
        uint4 mr;                                                           \
        mr = m0; { float vr = v[0];                                         \
            nv0 += vr * BF2F_LO(mr.x); nv1 += vr * BF2F_HI(mr.x);           \
            nv2 += vr * BF2F_LO(mr.y); nv3 += vr * BF2F_HI(mr.y);           \
            nv4 += vr * BF2F_LO(mr.z); nv5 += vr * BF2F_HI(mr.z);           \
            nv6 += vr * BF2F_LO(mr.w); nv7 += vr * BF2F_HI(mr.w); }         \
        mr = m1; { float vr = v[1];                                         \
            nv0 += vr * BF2F_LO(mr.x); nv1 += vr * BF2F_HI(mr.x);           \
            nv2 += vr * BF2F_LO(mr.y); nv3 += vr * BF2F_HI(mr.y);           \
            nv4 += vr * BF2F_LO(mr.z); nv5 += vr * BF2F_HI(mr.z);           \
            nv6 += vr * BF2F_LO(mr.w); nv7 += vr * BF2F_HI(mr.w); }         \
        mr = m2; { float vr = v[2];                                         \
            nv0 += vr * BF2F_LO(mr.x); nv1 += vr * BF2F_HI(mr.x);           \
            nv2 += vr * BF2F_LO(mr.y); nv3 += vr * BF2F_HI(mr.y);           \
            nv4 += vr * BF2F_LO(mr.z); nv5 += vr * BF2F_HI(mr.z);           \
            nv6 += vr * BF2F_LO(mr.w); nv7 += vr * BF2F_HI(mr.w); }         \
        mr = m3; { float vr = v[3];                                         \
            nv0 += vr * BF2F_LO(mr.x); nv1 += vr * BF2F_HI(mr.x);           \
            nv2 += vr * BF2F_LO(mr.y); nv3 += vr * BF2F_HI(mr.y);           \
            nv4 += vr * BF2F_LO(mr.z); nv5 += vr * BF2F_HI(mr.z);           \
            nv6 += vr * BF2F_LO(mr.w); nv7 += vr * BF2F_HI(mr.w); }         \
        mr = m4; { float vr = v[4];                                         \
            nv0 += vr * BF2F_LO(mr.x); nv1 += vr * BF2F_HI(mr.x);           \
            nv2 += vr * BF2F_LO(mr.y); nv3 += vr * BF2F_HI(mr.y);           \
            nv4 += vr * BF2F_LO(mr.z); nv5 += vr * BF2F_HI(mr.z);           \
            nv6 += vr * BF2F_LO(mr.w); nv7 += vr * BF2F_HI(mr.w); }         \
        mr = m5; { float vr = v[5];                                         \
            nv0 += vr * BF2F_LO(mr.x); nv1 += vr * BF2F_HI(mr.x);           \
            nv2 += vr * BF2F_LO(mr.y); nv3 += vr * BF2F_HI(mr.y);           \
            nv4 += vr * BF2F_LO(mr.z); nv5 += vr * BF2F_HI(mr.z);           \
            nv6 += vr * BF2F_LO(mr.w); nv7 += vr * BF2F_HI(mr.w); }         \
        mr = m6; { float vr = v[6];                                         \
            nv0 += vr * BF2F_LO(mr.x); nv1 += vr * BF2F_HI(mr.x);           \
            nv2 += vr * BF2F_LO(mr.y); nv3 += vr * BF2F_HI(mr.y);           \
            nv4 += vr * BF2F_LO(mr.z); nv5 += vr * BF2F_HI(mr.z);           \
            nv6 += vr * BF2F_LO(mr.w); nv7 += vr * BF2F_HI(mr.w); }         \
        mr = m7; { float vr = v[7];                                         \
            nv0 += vr * BF2F_LO(mr.x); nv1 += vr * BF2F_HI(mr.x);           \
            nv2 += vr * BF2F_LO(mr.y); nv3 += vr * BF2F_HI(mr.y);           \
            nv4 += vr * BF2F_LO(mr.z); nv5 += vr * BF2F_HI(mr.z);           \
            nv6 += vr * BF2F_LO(mr.w); nv7 += vr * BF2F_HI(mr.w); }         \
        v[0] = nv0; v[1] = nv1; v[2] = nv2; v[3] = nv3;                     \
        v[4] = nv4; v[5] = nv5; v[6] = nv6; v[7] = nv7;                     \
    } while (0)

__global__ __launch_bounds__(256) void tt_gather(
    const unsigned short* __restrict__ wsb,
    const int* __restrict__ states, const int* __restrict__ actions,
    float* __restrict__ out, int B) {
    __shared__ int ibuf[NN * 7];

    const int t = threadIdx.x;
    const int b = blockIdx.x * 256 + t;

    {
        const int* gsrc = states + (size_t)blockIdx.x * 256 * 7;
        const int lim = B * 7 - blockIdx.x * 256 * 7;
#pragma unroll
        for (int k = 0; k < 7; ++k) {
            int j = t + (k << 8);
            if (j < lim) ibuf[j] = gsrc[j];
        }
    }
    __syncthreads();

    const bool active = (b < B);
    const int* row = ibuf + t * 7;
    const int s0 = row[0] & 255;
    const int s1 = row[1] & 255;
    const int s2 = row[2] & 255;
    const int s3 = row[3] & 255;
    const int s4 = row[4] & 255;
    const int s5 = row[5] & 255;
    const int s6 = row[6] & 255;
    const int a7 = actions[active ? b : 0] & 255;

    // ---- issue ALL 18 independent gathers up front ----
    const uint4* pv = (const uint4*)(wsb + ((size_t)s0 * NN + s1) * 8);
    const uint4* pa = (const uint4*)(wsb + M23_OFF + ((size_t)s2 * NN + s3) * 64);
    const uint4* pb = (const uint4*)(wsb + M45_OFF + ((size_t)s4 * NN + s5) * 64);
    const uint4* pu = (const uint4*)(wsb + U67_OFF + ((size_t)s6 * NN + a7) * 8);

    uint4 uv = pv[0];
    uint4 a0 = pa[0], a1 = pa[1], a2 = pa[2], a3 = pa[3];
    uint4 a4 = pa[4], a5 = pa[5], a6 = pa[6], a7q = pa[7];
    uint4 b0 = pb[0], b1 = pb[1], b2 = pb[2], b3 = pb[3];
    uint4 b4 = pb[4], b5 = pb[5], b6 = pb[6], b7 = pb[7];
    uint4 uu = pu[0];

    float v[8];
    v[0] = BF2F_LO(uv.x); v[1] = BF2F_HI(uv.x);
    v[2] = BF2F_LO(uv.y); v[3] = BF2F_HI(uv.y);
    v[4] = BF2F_LO(uv.z); v[5] = BF2F_HI(uv.z);
    v[6] = BF2F_LO(uv.w); v[7] = BF2F_HI(uv.w);

    MATVEC(a0, a1, a2, a3, a4, a5, a6, a7q);
    MATVEC(b0, b1, b2, b3, b4, b5, b6, b7);

    float q = v[0] * BF2F_LO(uu.x) + v[1] * BF2F_HI(uu.x)
            + v[2] * BF2F_LO(uu.y) + v[3] * BF2F_HI(uu.y)
            + v[4] * BF2F_LO(uu.z) + v[5] * BF2F_HI(uu.z)
            + v[6] * BF2F_LO(uu.w) + v[7] * BF2F_HI(uu.w);
    if (active) out[b] = q;
}

extern "C" void kernel_launch(void* const* d_in, const int* in_sizes, int n_in,
                              void* d_out, int out_size, void* d_ws, size_t ws_size,
                              hipStream_t stream) {
    const float* G0 = (const float*)d_in[0];
    const float* G1 = (const float*)d_in[1];
    const float* G2 = (const float*)d_in[2];
    const float* G3 = (const float*)d_in[3];
    const float* G4 = (const float*)d_in[4];
    const float* G5 = (const float*)d_in[5];
    const float* G6 = (const float*)d_in[6];
    const float* G7 = (const float*)d_in[7];
    const int* states  = (const int*)d_in[8];
    const int* actions = (const int*)d_in[9];
    float* out = (float*)d_out;
    int B = in_sizes[9];

    unsigned short* wsb = (unsigned short*)d_ws;   // 18 MB used

    hipLaunchKernelGGL(build_tables, dim3(4 * NN), dim3(256), 0, stream,
                       G0, G1, G2, G3, G4, G5, G6, G7, wsb);

    hipLaunchKernelGGL(tt_gather, dim3((B + 255) / 256), dim3(256), 0, stream,
                       wsb, states, actions, out, B);
}